// Round 2
// baseline (975.940 us; speedup 1.0000x reference)
//
#include <hip/hip_runtime.h>
#include <hip/hip_bf16.h>
#include <hip/hip_fp16.h>

typedef _Float16 f16;
typedef _Float16 f16x2 __attribute__((ext_vector_type(2)));
typedef _Float16 f16x8 __attribute__((ext_vector_type(8)));
typedef float f32x4 __attribute__((ext_vector_type(4)));

#define BN_EPS 1e-5f

// ---------------- kernel 1: graph start offsets from sorted segment_ids ----------------
__global__ void seg_starts_k(const int* __restrict__ seg, int N, int G, int* __restrict__ start) {
    int n = blockIdx.x * blockDim.x + threadIdx.x;
    if (n >= N) return;
    int s = seg[n];
    int p = (n == 0) ? -1 : seg[n - 1];
    for (int g = p + 1; g <= s; ++g) start[g] = n;
    if (n == N - 1) {
        for (int g = s + 1; g <= G; ++g) start[g] = N;
    }
}

// ---------------- kernel 2: weight prep ----------------
// Folds BatchNorm (eval) of layer l into layer l+1's weights:
//   y_l = relu(x @ W + b);  h_l = y_l*s + c,  s = g*rsqrt(rv+eps), c = be - rm*s
//   h_l @ W_next = y_l @ (diag(s) W_next),  bias_next += c @ W_next
// Produces transposed fp16 weights Wt[l][t][o][i] and fp32 biases bp[l][t][o].
// grid = (T, 4); block = 128 (one thread per output column o)
__global__ void prep_k(const float* __restrict__ W1, const float* __restrict__ b1,
                       const float* __restrict__ W2, const float* __restrict__ b2,
                       const float* __restrict__ W3, const float* __restrict__ b3,
                       const float* __restrict__ oW1, const float* __restrict__ ob1,
                       const float* __restrict__ g1, const float* __restrict__ be1,
                       const float* __restrict__ rm1, const float* __restrict__ rv1,
                       const float* __restrict__ g2, const float* __restrict__ be2,
                       const float* __restrict__ rm2, const float* __restrict__ rv2,
                       const float* __restrict__ g3, const float* __restrict__ be3,
                       const float* __restrict__ rm3, const float* __restrict__ rv3,
                       f16* __restrict__ Wt, float* __restrict__ bp) {
    int T = gridDim.x;
    int t = blockIdx.x, l = blockIdx.y;
    int o = threadIdx.x;  // 0..127
    __shared__ float s_sh[128], c_sh[128];

    const float *W, *b, *gg = nullptr, *be = nullptr, *rm = nullptr, *rv = nullptr;
    if (l == 0)      { W = W1;  b = b1; }
    else if (l == 1) { W = W2;  b = b2;  gg = g1; be = be1; rm = rm1; rv = rv1; }
    else if (l == 2) { W = W3;  b = b3;  gg = g2; be = be2; rm = rm2; rv = rv2; }
    else             { W = oW1; b = ob1; gg = g3; be = be3; rm = rm3; rv = rv3; }

    float s = 1.f, c = 0.f;
    if (gg) {
        float sv = gg[t * 128 + o] * rsqrtf(rv[t * 128 + o] + BN_EPS);
        s = sv;
        c = be[t * 128 + o] - rm[t * 128 + o] * sv;
    }
    s_sh[o] = s;
    c_sh[o] = c;
    __syncthreads();

    const float* Wsrc = W + (size_t)t * 128 * 128;
    f16* Wdst = Wt + (((size_t)l * T + t) * 128 + o) * 128;  // [l][t][o][i]
    float acc = b[t * 128 + o];
    for (int i = 0; i < 128; ++i) {
        float wv = Wsrc[i * 128 + o];
        Wdst[i] = (f16)(s_sh[i] * wv);
        acc += c_sh[i] * wv;
    }
    bp[((size_t)l * T + t) * 128 + o] = acc;
}

// ---------------- kernel 3: fused sigmoid-weight + segment-sum pooling ----------------
// One wave per graph; lane owns features {2*lane, 2*lane+1}. mol layout [t][g][f] fp16.
__global__ __launch_bounds__(256) void pool_k(const float* __restrict__ feats,
                                              const float* __restrict__ atom_w,
                                              const float* __restrict__ atom_b,
                                              const int* __restrict__ start,
                                              f16* __restrict__ mol, int G) {
    int wave = threadIdx.x >> 6;
    int lane = threadIdx.x & 63;
    int g = blockIdx.x * 4 + wave;
    if (g >= G) return;

    float awx[12], awy[12], ab[12];
#pragma unroll
    for (int t = 0; t < 12; ++t) {
        awx[t] = atom_w[t * 128 + 2 * lane];
        awy[t] = atom_w[t * 128 + 2 * lane + 1];
        ab[t] = atom_b[t];
    }
    float accx[12], accy[12];
#pragma unroll
    for (int t = 0; t < 12; ++t) { accx[t] = 0.f; accy[t] = 0.f; }

    int a0 = start[g], a1 = start[g + 1];
    for (int a = a0; a < a1; ++a) {
        const float2 x = *(const float2*)(feats + (size_t)a * 128 + 2 * lane);
        float p[12];
#pragma unroll
        for (int t = 0; t < 12; ++t) p[t] = x.x * awx[t] + x.y * awy[t];
#pragma unroll
        for (int m = 1; m < 64; m <<= 1) {
#pragma unroll
            for (int t = 0; t < 12; ++t) p[t] += __shfl_xor(p[t], m, 64);
        }
#pragma unroll
        for (int t = 0; t < 12; ++t) {
            float w = 1.f / (1.f + __expf(-(p[t] + ab[t])));
            accx[t] += w * x.x;
            accy[t] += w * x.y;
        }
    }
#pragma unroll
    for (int t = 0; t < 12; ++t) {
        f16x2 h;
        h.x = (f16)accx[t];
        h.y = (f16)accy[t];
        *(f16x2*)(mol + ((size_t)t * G + g) * 128 + 2 * lane) = h;
    }
}

// ---------------- kernel 4: fused 4-layer MLP + final dot, fp16 MFMA ----------------
// grid = (ceil(G/64), T), block = 256 (4 waves, each owns 16 rows).
// LDS: A ping-pong 2x[64][128] f16 (32KB) + B [128][128] f16 (32KB) = 64KB -> 2 blocks/CU.
// Rows are 128 f16 = 16 slots of 8 elements (16B). XOR swizzle: stored_slot =
// orig_slot ^ (row&7) -> conflict-free ds_read_b128 down columns (G4).
__global__ __launch_bounds__(256, 2) void fc_k(const f16* __restrict__ mol,
                                               const f16* __restrict__ Wt,
                                               const float* __restrict__ bp,
                                               const float* __restrict__ oW2,
                                               const float* __restrict__ ob2,
                                               float* __restrict__ out, int G, int T) {
    __shared__ f16 A[2][64][128];
    __shared__ f16 B[128][128];

    int t = blockIdx.y;
    int g0 = blockIdx.x * 64;
    int tid = threadIdx.x;

    // load A tile (mol): 64 rows x 16 slots = 1024 chunks of 16B
    {
        const f16* src = mol + (size_t)t * G * 128;
#pragma unroll
        for (int k = 0; k < 4; ++k) {
            int c = tid + k * 256;          // 0..1023
            int r = c >> 4, sl = c & 15;
            uint4 v = make_uint4(0u, 0u, 0u, 0u);
            if (g0 + r < G) v = *(const uint4*)(src + (size_t)(g0 + r) * 128 + sl * 8);
            *(uint4*)(&A[0][r][(sl ^ (r & 7)) * 8]) = v;
        }
    }
    // load B for layer 0: 128 rows x 16 slots = 2048 chunks of 16B
    {
        const f16* src = Wt + ((size_t)0 * T + t) * 128 * 128;
#pragma unroll
        for (int k = 0; k < 8; ++k) {
            int c = tid + k * 256;          // 0..2047
            int r = c >> 4, sl = c & 15;
            uint4 v = *(const uint4*)(src + (size_t)r * 128 + sl * 8);
            *(uint4*)(&B[r][(sl ^ (r & 7)) * 8]) = v;
        }
    }
    __syncthreads();

    int wid = tid >> 6, lane = tid & 63;
    int lg = lane >> 4, lr = lane & 15;
    int m0 = wid * 16;
    int arow = m0 + lr;
    float pred[4] = {0.f, 0.f, 0.f, 0.f};
    int cur = 0;

    for (int l = 0; l < 4; ++l) {
        f16x8 afr[4];
#pragma unroll
        for (int ks = 0; ks < 4; ++ks) {
            int sl = (4 * ks + lg) ^ (arow & 7);
            afr[ks] = *(const f16x8*)(&A[cur][arow][sl * 8]);
        }
        const float* bias = bp + ((size_t)l * T + t) * 128;
#pragma unroll
        for (int nf = 0; nf < 8; ++nf) {
            int n = nf * 16 + lr;
            f32x4 acc = {0.f, 0.f, 0.f, 0.f};
#pragma unroll
            for (int ks = 0; ks < 4; ++ks) {
                int sl = (4 * ks + lg) ^ (n & 7);
                f16x8 bfr = *(const f16x8*)(&B[n][sl * 8]);
                acc = __builtin_amdgcn_mfma_f32_16x16x32_f16(afr[ks], bfr, acc, 0, 0, 0);
            }
            float bv = bias[n];
            if (l < 3) {
#pragma unroll
                for (int j = 0; j < 4; ++j) {
                    float y = acc[j] + bv;
                    y = y > 0.f ? y : 0.f;
                    int rr = m0 + 4 * lg + j;
                    A[cur ^ 1][rr][(((n >> 3) ^ (rr & 7)) << 3) + (n & 7)] = (f16)y;
                }
            } else {
                float w2 = oW2[t * 128 + n];
#pragma unroll
                for (int j = 0; j < 4; ++j) {
                    float z = acc[j] + bv;
                    z = z > 0.f ? z : 0.f;
                    pred[j] += z * w2;
                }
            }
        }
        __syncthreads();
        if (l < 3) {
            const f16* src = Wt + ((size_t)(l + 1) * T + t) * 128 * 128;
#pragma unroll
            for (int k = 0; k < 8; ++k) {
                int c = tid + k * 256;
                int r = c >> 4, sl = c & 15;
                uint4 v = *(const uint4*)(src + (size_t)r * 128 + sl * 8);
                *(uint4*)(&B[r][(sl ^ (r & 7)) * 8]) = v;
            }
            __syncthreads();
            cur ^= 1;
        }
    }

    // reduce pred over the 16 col-lanes (o dimension)
#pragma unroll
    for (int m = 1; m < 16; m <<= 1) {
#pragma unroll
        for (int j = 0; j < 4; ++j) pred[j] += __shfl_xor(pred[j], m, 64);
    }
    if (lr == 0) {
        float ob = ob2[t];
#pragma unroll
        for (int j = 0; j < 4; ++j) {
            int gg = g0 + m0 + 4 * lg + j;
            if (gg < G) out[(size_t)gg * T + t] = pred[j] + ob;
        }
    }
}

extern "C" void kernel_launch(void* const* d_in, const int* in_sizes, int n_in,
                              void* d_out, int out_size, void* d_ws, size_t ws_size,
                              hipStream_t stream) {
    const float* node_feats = (const float*)d_in[0];
    const int*   seg        = (const int*)d_in[1];
    // d_in[2] = num_graphs (device scalar, derived from out_size instead)
    const float* atom_w     = (const float*)d_in[3];
    const float* atom_b     = (const float*)d_in[4];
    const float* W1  = (const float*)d_in[5];
    const float* b1  = (const float*)d_in[6];
    const float* g1  = (const float*)d_in[7];
    const float* be1 = (const float*)d_in[8];
    const float* rm1 = (const float*)d_in[9];
    const float* rv1 = (const float*)d_in[10];
    const float* W2  = (const float*)d_in[11];
    const float* b2  = (const float*)d_in[12];
    const float* g2  = (const float*)d_in[13];
    const float* be2 = (const float*)d_in[14];
    const float* rm2 = (const float*)d_in[15];
    const float* rv2 = (const float*)d_in[16];
    const float* W3  = (const float*)d_in[17];
    const float* b3  = (const float*)d_in[18];
    const float* g3  = (const float*)d_in[19];
    const float* be3 = (const float*)d_in[20];
    const float* rm3 = (const float*)d_in[21];
    const float* rv3 = (const float*)d_in[22];
    const float* oW1 = (const float*)d_in[23];
    const float* ob1 = (const float*)d_in[24];
    const float* oW2 = (const float*)d_in[25];
    const float* ob2 = (const float*)d_in[26];

    int T = in_sizes[4];          // 12
    int F = in_sizes[3] / T;      // 128
    int N = in_sizes[0] / F;      // 1,000,000
    int G = out_size / T;         // 50,000

    char* ws = (char*)d_ws;
    size_t off = 0;
    int* start = (int*)ws;
    off += (((size_t)(G + 1) * 4) + 255) & ~(size_t)255;
    f16* Wt = (f16*)(ws + off);
    off += (((size_t)4 * T * 128 * 128 * 2) + 255) & ~(size_t)255;
    float* bp = (float*)(ws + off);
    off += (((size_t)4 * T * 128 * 4) + 255) & ~(size_t)255;
    f16* mol = (f16*)(ws + off);
    // off += (size_t)T * G * 128 * 2;

    seg_starts_k<<<(N + 255) / 256, 256, 0, stream>>>(seg, N, G, start);
    prep_k<<<dim3(T, 4), 128, 0, stream>>>(W1, b1, W2, b2, W3, b3, oW1, ob1,
                                           g1, be1, rm1, rv1,
                                           g2, be2, rm2, rv2,
                                           g3, be3, rm3, rv3, Wt, bp);
    pool_k<<<(G + 3) / 4, 256, 0, stream>>>(node_feats, atom_w, atom_b, start, mol, G);
    fc_k<<<dim3((G + 63) / 64, T), 256, 0, stream>>>(mol, Wt, bp, oW2, ob2,
                                                     (float*)d_out, G, T);
}

// Round 3
// 402.079 us; speedup vs baseline: 2.4272x; 2.4272x over previous
//
#include <hip/hip_runtime.h>
#include <hip/hip_bf16.h>
#include <hip/hip_fp16.h>

typedef _Float16 f16;
typedef _Float16 f16x2 __attribute__((ext_vector_type(2)));
typedef _Float16 f16x4 __attribute__((ext_vector_type(4)));
typedef _Float16 f16x8 __attribute__((ext_vector_type(8)));
typedef float f32x4 __attribute__((ext_vector_type(4)));

#define BN_EPS 1e-5f

// ---------------- kernel 1: graph start offsets from sorted segment_ids ----------------
__global__ void seg_starts_k(const int* __restrict__ seg, int N, int G, int* __restrict__ start) {
    int n = blockIdx.x * blockDim.x + threadIdx.x;
    if (n >= N) return;
    int s = seg[n];
    int p = (n == 0) ? -1 : seg[n - 1];
    for (int g = p + 1; g <= s; ++g) start[g] = n;
    if (n == N - 1) {
        for (int g = s + 1; g <= G; ++g) start[g] = N;
    }
}

// ---------------- kernel 2: weight prep (BN folding, fp16 transpose) ----------------
__global__ void prep_k(const float* __restrict__ W1, const float* __restrict__ b1,
                       const float* __restrict__ W2, const float* __restrict__ b2,
                       const float* __restrict__ W3, const float* __restrict__ b3,
                       const float* __restrict__ oW1, const float* __restrict__ ob1,
                       const float* __restrict__ g1, const float* __restrict__ be1,
                       const float* __restrict__ rm1, const float* __restrict__ rv1,
                       const float* __restrict__ g2, const float* __restrict__ be2,
                       const float* __restrict__ rm2, const float* __restrict__ rv2,
                       const float* __restrict__ g3, const float* __restrict__ be3,
                       const float* __restrict__ rm3, const float* __restrict__ rv3,
                       f16* __restrict__ Wt, float* __restrict__ bp) {
    int T = gridDim.x;
    int t = blockIdx.x, l = blockIdx.y;
    int o = threadIdx.x;  // 0..127
    __shared__ float s_sh[128], c_sh[128];

    const float *W, *b, *gg = nullptr, *be = nullptr, *rm = nullptr, *rv = nullptr;
    if (l == 0)      { W = W1;  b = b1; }
    else if (l == 1) { W = W2;  b = b2;  gg = g1; be = be1; rm = rm1; rv = rv1; }
    else if (l == 2) { W = W3;  b = b3;  gg = g2; be = be2; rm = rm2; rv = rv2; }
    else             { W = oW1; b = ob1; gg = g3; be = be3; rm = rm3; rv = rv3; }

    float s = 1.f, c = 0.f;
    if (gg) {
        float sv = gg[t * 128 + o] * rsqrtf(rv[t * 128 + o] + BN_EPS);
        s = sv;
        c = be[t * 128 + o] - rm[t * 128 + o] * sv;
    }
    s_sh[o] = s;
    c_sh[o] = c;
    __syncthreads();

    const float* Wsrc = W + (size_t)t * 128 * 128;
    f16* Wdst = Wt + (((size_t)l * T + t) * 128 + o) * 128;  // [l][t][o][i]
    float acc = b[t * 128 + o];
    for (int i = 0; i < 128; ++i) {
        float wv = Wsrc[i * 128 + o];
        Wdst[i] = (f16)(s_sh[i] * wv);
        acc += c_sh[i] * wv;
    }
    bp[((size_t)l * T + t) * 128 + o] = acc;
}

// ---------------- kernel 3: fused pooling, MFMA weights, zero butterflies ----------------
// One wave per graph. Chunks of 16 atoms:
//  A) stage 16x128 f32->f16 into wave-private LDS tile (swizzled slots)
//  B) one MFMA chain (16x16x32 f16, K=128): p[atom][task] = x . aw_t; sigmoid -> wsh
//  C) lane = feature pair: acc[t] += w[a][t]*x[a][f], broadcast w reads.
// No __syncthreads (waves diverge); wave-internal ordering via s_waitcnt lgkmcnt(0).
__global__ __launch_bounds__(256) void pool_k(const float* __restrict__ feats,
                                              const float* __restrict__ atom_w,
                                              const float* __restrict__ atom_b,
                                              const int* __restrict__ start,
                                              f16* __restrict__ mol, int G) {
    __shared__ f16 xs_all[4][16][128];     // 4KB/wave
    __shared__ float ws_all[4][16][16];    // 1KB/wave

    int wave = threadIdx.x >> 6;
    int lane = threadIdx.x & 63;
    f16 (*xs)[128] = xs_all[wave];
    float (*wsh)[16] = ws_all[wave];

    int g = blockIdx.x * 4 + wave;
    if (g >= G) return;

    int tcol = lane & 15;   // task col for MFMA B / output row for A
    int kg = lane >> 4;     // k-group

    // B-fragment: atom_w[t][k], t = tcol (pad 12..15 with zeros), k = ks*32+kg*8+j
    f16x8 bfr[4];
    float ab = 0.f;
#pragma unroll
    for (int ks = 0; ks < 4; ++ks) {
        f16x8 v = {};
        if (tcol < 12) {
            const float* s = atom_w + tcol * 128 + ks * 32 + kg * 8;
#pragma unroll
            for (int j = 0; j < 8; ++j) v[j] = (f16)s[j];
        }
        bfr[ks] = v;
    }
    if (tcol < 12) ab = atom_b[tcol];

    float accx[12], accy[12];
#pragma unroll
    for (int t = 0; t < 12; ++t) { accx[t] = 0.f; accy[t] = 0.f; }

    int a0 = start[g], a1 = start[g + 1];

    for (int c0 = a0; c0 < a1; c0 += 16) {
        int cn = a1 - c0; if (cn > 16) cn = 16;
        // WAR guard: previous chunk's reads must retire before overwriting xs
        asm volatile("s_waitcnt lgkmcnt(0)" ::: "memory");
        __builtin_amdgcn_sched_barrier(0);

        // A) stage 16 rows x 32 float4 = 512 chunks, 8 iters
#pragma unroll
        for (int it = 0; it < 8; ++it) {
            int c = (it << 6) + lane;       // 0..511
            int r = c >> 5, q = c & 31;     // row, float4 index
            float4 u = make_float4(0.f, 0.f, 0.f, 0.f);
            if (r < cn) u = *(const float4*)(feats + (size_t)(c0 + r) * 128 + (q << 2));
            f16x4 h;
            h[0] = (f16)u.x; h[1] = (f16)u.y; h[2] = (f16)u.z; h[3] = (f16)u.w;
            *(f16x4*)(&xs[r][(((q >> 1) ^ (r & 7)) << 3) + ((q & 1) << 2)]) = h;
        }
        asm volatile("s_waitcnt lgkmcnt(0)" ::: "memory");
        __builtin_amdgcn_sched_barrier(0);

        // B) MFMA: p[atom][task]
        f32x4 pa = {0.f, 0.f, 0.f, 0.f};
#pragma unroll
        for (int ks = 0; ks < 4; ++ks) {
            f16x8 afr = *(const f16x8*)(&xs[tcol][((((ks << 2) + kg)) ^ (tcol & 7)) << 3]);
            pa = __builtin_amdgcn_mfma_f32_16x16x32_f16(afr, bfr[ks], pa, 0, 0, 0);
        }
        // pa[j]: atom row = kg*4+j, task col = tcol
#pragma unroll
        for (int j = 0; j < 4; ++j) {
            float w = 1.f / (1.f + __expf(-(pa[j] + ab)));
            wsh[(kg << 2) + j][tcol] = w;
        }
        asm volatile("s_waitcnt lgkmcnt(0)" ::: "memory");
        __builtin_amdgcn_sched_barrier(0);

        // C) weighted accumulate; lane owns feats {2*lane, 2*lane+1}
        for (int a = 0; a < cn; ++a) {
            f16x2 x2 = *(const f16x2*)(&xs[a][(((lane >> 2) ^ (a & 7)) << 3) + ((lane & 3) << 1)]);
            float x0 = (float)x2[0], x1 = (float)x2[1];
            f32x4 w0 = *(const f32x4*)(&wsh[a][0]);
            f32x4 w1 = *(const f32x4*)(&wsh[a][4]);
            f32x4 w2 = *(const f32x4*)(&wsh[a][8]);
#pragma unroll
            for (int j = 0; j < 4; ++j) {
                accx[j] += w0[j] * x0;     accy[j] += w0[j] * x1;
                accx[4 + j] += w1[j] * x0; accy[4 + j] += w1[j] * x1;
                accx[8 + j] += w2[j] * x0; accy[8 + j] += w2[j] * x1;
            }
        }
    }

#pragma unroll
    for (int t = 0; t < 12; ++t) {
        f16x2 h;
        h[0] = (f16)accx[t];
        h[1] = (f16)accy[t];
        *(f16x2*)(mol + ((size_t)t * G + g) * 128 + 2 * lane) = h;
    }
}

// ---------------- kernel 4: fused 4-layer MLP + final dot, fp16 MFMA ----------------
__global__ __launch_bounds__(256, 2) void fc_k(const f16* __restrict__ mol,
                                               const f16* __restrict__ Wt,
                                               const float* __restrict__ bp,
                                               const float* __restrict__ oW2,
                                               const float* __restrict__ ob2,
                                               float* __restrict__ out, int G, int T) {
    __shared__ f16 A[2][64][128];
    __shared__ f16 B[128][128];

    int t = blockIdx.y;
    int g0 = blockIdx.x * 64;
    int tid = threadIdx.x;

    // load A tile (mol): 64 rows x 16 slots = 1024 chunks of 16B
    {
        const f16* src = mol + (size_t)t * G * 128;
#pragma unroll
        for (int k = 0; k < 4; ++k) {
            int c = tid + k * 256;          // 0..1023
            int r = c >> 4, sl = c & 15;
            uint4 v = make_uint4(0u, 0u, 0u, 0u);
            if (g0 + r < G) v = *(const uint4*)(src + (size_t)(g0 + r) * 128 + sl * 8);
            *(uint4*)(&A[0][r][(sl ^ (r & 7)) * 8]) = v;
        }
    }
    // load B for layer 0: 128 rows x 16 slots = 2048 chunks of 16B
    {
        const f16* src = Wt + ((size_t)0 * T + t) * 128 * 128;
#pragma unroll
        for (int k = 0; k < 8; ++k) {
            int c = tid + k * 256;          // 0..2047
            int r = c >> 4, sl = c & 15;
            uint4 v = *(const uint4*)(src + (size_t)r * 128 + sl * 8);
            *(uint4*)(&B[r][(sl ^ (r & 7)) * 8]) = v;
        }
    }
    __syncthreads();

    int wid = tid >> 6, lane = tid & 63;
    int lg = lane >> 4, lr = lane & 15;
    int m0 = wid * 16;
    int arow = m0 + lr;
    float pred[4] = {0.f, 0.f, 0.f, 0.f};
    int cur = 0;

    for (int l = 0; l < 4; ++l) {
        f16x8 afr[4];
#pragma unroll
        for (int ks = 0; ks < 4; ++ks) {
            int sl = (4 * ks + lg) ^ (arow & 7);
            afr[ks] = *(const f16x8*)(&A[cur][arow][sl * 8]);
        }
        const float* bias = bp + ((size_t)l * T + t) * 128;
#pragma unroll
        for (int nf = 0; nf < 8; ++nf) {
            int n = nf * 16 + lr;
            f32x4 acc = {0.f, 0.f, 0.f, 0.f};
#pragma unroll
            for (int ks = 0; ks < 4; ++ks) {
                int sl = (4 * ks + lg) ^ (n & 7);
                f16x8 bfr = *(const f16x8*)(&B[n][sl * 8]);
                acc = __builtin_amdgcn_mfma_f32_16x16x32_f16(afr[ks], bfr, acc, 0, 0, 0);
            }
            float bv = bias[n];
            if (l < 3) {
#pragma unroll
                for (int j = 0; j < 4; ++j) {
                    float y = acc[j] + bv;
                    y = y > 0.f ? y : 0.f;
                    int rr = m0 + 4 * lg + j;
                    A[cur ^ 1][rr][(((n >> 3) ^ (rr & 7)) << 3) + (n & 7)] = (f16)y;
                }
            } else {
                float w2 = oW2[t * 128 + n];
#pragma unroll
                for (int j = 0; j < 4; ++j) {
                    float z = acc[j] + bv;
                    z = z > 0.f ? z : 0.f;
                    pred[j] += z * w2;
                }
            }
        }
        __syncthreads();
        if (l < 3) {
            const f16* src = Wt + ((size_t)(l + 1) * T + t) * 128 * 128;
#pragma unroll
            for (int k = 0; k < 8; ++k) {
                int c = tid + k * 256;
                int r = c >> 4, sl = c & 15;
                uint4 v = *(const uint4*)(src + (size_t)r * 128 + sl * 8);
                *(uint4*)(&B[r][(sl ^ (r & 7)) * 8]) = v;
            }
            __syncthreads();
            cur ^= 1;
        }
    }

#pragma unroll
    for (int m = 1; m < 16; m <<= 1) {
#pragma unroll
        for (int j = 0; j < 4; ++j) pred[j] += __shfl_xor(pred[j], m, 64);
    }
    if (lr == 0) {
        float ob = ob2[t];
#pragma unroll
        for (int j = 0; j < 4; ++j) {
            int gg = g0 + m0 + 4 * lg + j;
            if (gg < G) out[(size_t)gg * T + t] = pred[j] + ob;
        }
    }
}

extern "C" void kernel_launch(void* const* d_in, const int* in_sizes, int n_in,
                              void* d_out, int out_size, void* d_ws, size_t ws_size,
                              hipStream_t stream) {
    const float* node_feats = (const float*)d_in[0];
    const int*   seg        = (const int*)d_in[1];
    const float* atom_w     = (const float*)d_in[3];
    const float* atom_b     = (const float*)d_in[4];
    const float* W1  = (const float*)d_in[5];
    const float* b1  = (const float*)d_in[6];
    const float* g1  = (const float*)d_in[7];
    const float* be1 = (const float*)d_in[8];
    const float* rm1 = (const float*)d_in[9];
    const float* rv1 = (const float*)d_in[10];
    const float* W2  = (const float*)d_in[11];
    const float* b2  = (const float*)d_in[12];
    const float* g2  = (const float*)d_in[13];
    const float* be2 = (const float*)d_in[14];
    const float* rm2 = (const float*)d_in[15];
    const float* rv2 = (const float*)d_in[16];
    const float* W3  = (const float*)d_in[17];
    const float* b3  = (const float*)d_in[18];
    const float* g3  = (const float*)d_in[19];
    const float* be3 = (const float*)d_in[20];
    const float* rm3 = (const float*)d_in[21];
    const float* rv3 = (const float*)d_in[22];
    const float* oW1 = (const float*)d_in[23];
    const float* ob1 = (const float*)d_in[24];
    const float* oW2 = (const float*)d_in[25];
    const float* ob2 = (const float*)d_in[26];

    int T = in_sizes[4];          // 12
    int F = in_sizes[3] / T;      // 128
    int N = in_sizes[0] / F;      // 1,000,000
    int G = out_size / T;         // 50,000

    char* ws = (char*)d_ws;
    size_t off = 0;
    int* start = (int*)ws;
    off += (((size_t)(G + 1) * 4) + 255) & ~(size_t)255;
    f16* Wt = (f16*)(ws + off);
    off += (((size_t)4 * T * 128 * 128 * 2) + 255) & ~(size_t)255;
    float* bp = (float*)(ws + off);
    off += (((size_t)4 * T * 128 * 4) + 255) & ~(size_t)255;
    f16* mol = (f16*)(ws + off);

    seg_starts_k<<<(N + 255) / 256, 256, 0, stream>>>(seg, N, G, start);
    prep_k<<<dim3(T, 4), 128, 0, stream>>>(W1, b1, W2, b2, W3, b3, oW1, ob1,
                                           g1, be1, rm1, rv1,
                                           g2, be2, rm2, rv2,
                                           g3, be3, rm3, rv3, Wt, bp);
    pool_k<<<(G + 3) / 4, 256, 0, stream>>>(node_feats, atom_w, atom_b, start, mol, G);
    fc_k<<<dim3((G + 63) / 64, T), 256, 0, stream>>>(mol, Wt, bp, oW2, ob2,
                                                     (float*)d_out, G, T);
}

// Round 4
// 372.567 us; speedup vs baseline: 2.6195x; 1.0792x over previous
//
#include <hip/hip_runtime.h>
#include <hip/hip_bf16.h>
#include <hip/hip_fp16.h>

typedef _Float16 f16;
typedef _Float16 f16x2 __attribute__((ext_vector_type(2)));
typedef _Float16 f16x4 __attribute__((ext_vector_type(4)));
typedef _Float16 f16x8 __attribute__((ext_vector_type(8)));
typedef float f32x4 __attribute__((ext_vector_type(4)));

#define BN_EPS 1e-5f

// ---------------- kernel 1: graph start offsets from sorted segment_ids ----------------
__global__ void seg_starts_k(const int* __restrict__ seg, int N, int G, int* __restrict__ start) {
    int n = blockIdx.x * blockDim.x + threadIdx.x;
    if (n >= N) return;
    int s = seg[n];
    int p = (n == 0) ? -1 : seg[n - 1];
    for (int g = p + 1; g <= s; ++g) start[g] = n;
    if (n == N - 1) {
        for (int g = s + 1; g <= G; ++g) start[g] = N;
    }
}

// ---------------- kernel 2: weight prep (BN folding, fp16 transpose) ----------------
__global__ void prep_k(const float* __restrict__ W1, const float* __restrict__ b1,
                       const float* __restrict__ W2, const float* __restrict__ b2,
                       const float* __restrict__ W3, const float* __restrict__ b3,
                       const float* __restrict__ oW1, const float* __restrict__ ob1,
                       const float* __restrict__ g1, const float* __restrict__ be1,
                       const float* __restrict__ rm1, const float* __restrict__ rv1,
                       const float* __restrict__ g2, const float* __restrict__ be2,
                       const float* __restrict__ rm2, const float* __restrict__ rv2,
                       const float* __restrict__ g3, const float* __restrict__ be3,
                       const float* __restrict__ rm3, const float* __restrict__ rv3,
                       f16* __restrict__ Wt, float* __restrict__ bp) {
    int T = gridDim.x;
    int t = blockIdx.x, l = blockIdx.y;
    int o = threadIdx.x;  // 0..127
    __shared__ float s_sh[128], c_sh[128];

    const float *W, *b, *gg = nullptr, *be = nullptr, *rm = nullptr, *rv = nullptr;
    if (l == 0)      { W = W1;  b = b1; }
    else if (l == 1) { W = W2;  b = b2;  gg = g1; be = be1; rm = rm1; rv = rv1; }
    else if (l == 2) { W = W3;  b = b3;  gg = g2; be = be2; rm = rm2; rv = rv2; }
    else             { W = oW1; b = ob1; gg = g3; be = be3; rm = rm3; rv = rv3; }

    float s = 1.f, c = 0.f;
    if (gg) {
        float sv = gg[t * 128 + o] * rsqrtf(rv[t * 128 + o] + BN_EPS);
        s = sv;
        c = be[t * 128 + o] - rm[t * 128 + o] * sv;
    }
    s_sh[o] = s;
    c_sh[o] = c;
    __syncthreads();

    const float* Wsrc = W + (size_t)t * 128 * 128;
    f16* Wdst = Wt + (((size_t)l * T + t) * 128 + o) * 128;  // [l][t][o][i]
    float acc = b[t * 128 + o];
    for (int i = 0; i < 128; ++i) {
        float wv = Wsrc[i * 128 + o];
        Wdst[i] = (f16)(s_sh[i] * wv);
        acc += c_sh[i] * wv;
    }
    bp[((size_t)l * T + t) * 128 + o] = acc;
}

// ---------------- kernel 3: fully-MFMA fused pooling ----------------
// One wave per graph, chunks of 16 atoms, double-buffered wave-private LDS.
// Per chunk:
//  A) (prefetched) 8 float4/lane -> cvt -> ds_write xs[buf] (swizzled)
//  B) weight MFMA chain (16x16x32_f16, K=128): pa[atom][task]; sigmoid in-reg.
//     pa fragment (row=atom,col=task) == A-operand layout of 16x16x16_f16
//     (row=task, k=atom) -> no cross-lane redistribution.
//  C) 8x mfma_f32_16x16x16f16(w_frag, x_frag, acc[nf]): mol[t][f] += w[a][t]x[a][f]
// Output mol layout: [g][t][f] f16 (3KB contiguous per graph).
__global__ __launch_bounds__(256) void pool_k(const float* __restrict__ feats,
                                              const float* __restrict__ atom_w,
                                              const float* __restrict__ atom_b,
                                              const int* __restrict__ start,
                                              f16* __restrict__ mol, int G) {
    __shared__ f16 xs_all[4][2][16][128];   // 8KB/wave double-buffered, 32KB/block

    int wave = threadIdx.x >> 6;
    int lane = threadIdx.x & 63;
    f16 (*xs)[16][128] = xs_all[wave];

    int g = blockIdx.x * 4 + wave;
    if (g >= G) return;

    int lr = lane & 15;   // task col (B), row (A/B2 frags)
    int kg = lane >> 4;   // k-group

    // B-fragment for weight MFMA: atom_w[t=lr][k], zero-padded tasks 12..15
    f16x8 bfr[4];
    float ab = 0.f;
#pragma unroll
    for (int ks = 0; ks < 4; ++ks) {
        f16x8 v = {};
        if (lr < 12) {
            const float* s = atom_w + lr * 128 + ks * 32 + kg * 8;
#pragma unroll
            for (int j = 0; j < 8; ++j) v[j] = (f16)s[j];
        }
        bfr[ks] = v;
    }
    if (lr < 12) ab = atom_b[lr];

    f32x4 acc[8];
#pragma unroll
    for (int nf = 0; nf < 8; ++nf) acc[nf] = (f32x4){0.f, 0.f, 0.f, 0.f};

    int a0 = start[g], a1 = start[g + 1];
    int nAtoms = a1 - a0;
    int nc = (nAtoms + 15) >> 4;

    float4 u[8];
    // prologue: issue chunk-0 loads (zero-fill rows >= cn to avoid NaN garbage)
    if (nc > 0) {
        int cn = nAtoms < 16 ? nAtoms : 16;
#pragma unroll
        for (int it = 0; it < 8; ++it) {
            int c = (it << 6) + lane;
            int r = c >> 5, q = c & 31;
            float4 v = make_float4(0.f, 0.f, 0.f, 0.f);
            if (r < cn) v = *(const float4*)(feats + (size_t)(a0 + r) * 128 + (q << 2));
            u[it] = v;
        }
    }

    for (int ci = 0; ci < nc; ++ci) {
        int cur = ci & 1;
        // A) write staged chunk into xs[cur] (swizzled slots)
#pragma unroll
        for (int it = 0; it < 8; ++it) {
            int c = (it << 6) + lane;
            int r = c >> 5, q = c & 31;
            f16x4 h;
            h[0] = (f16)u[it].x; h[1] = (f16)u[it].y;
            h[2] = (f16)u[it].z; h[3] = (f16)u[it].w;
            *(f16x4*)(&xs[cur][r][(((q >> 1) ^ (r & 7)) << 3) + ((q & 1) << 2)]) = h;
        }
        // prefetch next chunk (issue early; consumed after phases B/C)
        if (ci + 1 < nc) {
            int c0 = a0 + (ci + 1) * 16;
            int cn2 = a1 - c0; if (cn2 > 16) cn2 = 16;
#pragma unroll
            for (int it = 0; it < 8; ++it) {
                int c = (it << 6) + lane;
                int r = c >> 5, q = c & 31;
                float4 v = make_float4(0.f, 0.f, 0.f, 0.f);
                if (r < cn2) v = *(const float4*)(feats + (size_t)(c0 + r) * 128 + (q << 2));
                u[it] = v;
            }
        }
        int cn = nAtoms - ci * 16; if (cn > 16) cn = 16;

        // B) weight MFMA: pa[row=atom=(kg*4+j)][col=task=lr]
        f32x4 pa = {0.f, 0.f, 0.f, 0.f};
#pragma unroll
        for (int ks = 0; ks < 4; ++ks) {
            f16x8 afr = *(const f16x8*)(&xs[cur][lr][((((ks << 2) + kg)) ^ (lr & 7)) << 3]);
            pa = __builtin_amdgcn_mfma_f32_16x16x32_f16(afr, bfr[ks], pa, 0, 0, 0);
        }
        // sigmoid -> A-frag of pooling MFMA (row=task=lr, k=atom=(kg*4+j))
        f16x4 a2;
#pragma unroll
        for (int j = 0; j < 4; ++j) {
            float w = 1.f / (1.f + __expf(-(pa[j] + ab)));
            int atom = (kg << 2) + j;
            a2[j] = (atom < cn) ? (f16)w : (f16)0.f;
        }
        // C) pooling MFMAs: acc[nf][t][f] += w^T x
#pragma unroll
        for (int nf = 0; nf < 8; ++nf) {
            f16x4 b2;
#pragma unroll
            for (int j = 0; j < 4; ++j) {
                int a = (kg << 2) + j;
                int f = (nf << 4) + lr;
                b2[j] = xs[cur][a][(((f >> 3) ^ (a & 7)) << 3) + (f & 7)];
            }
            acc[nf] = __builtin_amdgcn_mfma_f32_16x16x16f16(a2, b2, acc[nf], 0, 0, 0);
        }
    }

    // store mol[g][t][f]: row t = 4*kg+j (kg<3 valid), col f = nf*16+lr
    f16* dst = mol + (size_t)g * 12 * 128;
    if (kg < 3) {
#pragma unroll
        for (int nf = 0; nf < 8; ++nf) {
#pragma unroll
            for (int j = 0; j < 4; ++j) {
                dst[((kg << 2) + j) * 128 + (nf << 4) + lr] = (f16)acc[nf][j];
            }
        }
    }
}

// ---------------- kernel 4: fused 4-layer MLP + final dot, fp16 MFMA ----------------
// mol layout now [g][t][f].
__global__ __launch_bounds__(256, 2) void fc_k(const f16* __restrict__ mol,
                                               const f16* __restrict__ Wt,
                                               const float* __restrict__ bp,
                                               const float* __restrict__ oW2,
                                               const float* __restrict__ ob2,
                                               float* __restrict__ out, int G, int T) {
    __shared__ f16 A[2][64][128];
    __shared__ f16 B[128][128];

    int t = blockIdx.y;
    int g0 = blockIdx.x * 64;
    int tid = threadIdx.x;

    // load A tile: 64 rows x 16 slots of 16B
    {
#pragma unroll
        for (int k = 0; k < 4; ++k) {
            int c = tid + k * 256;          // 0..1023
            int r = c >> 4, sl = c & 15;
            uint4 v = make_uint4(0u, 0u, 0u, 0u);
            if (g0 + r < G)
                v = *(const uint4*)(mol + ((size_t)(g0 + r) * T + t) * 128 + sl * 8);
            *(uint4*)(&A[0][r][(sl ^ (r & 7)) * 8]) = v;
        }
    }
    // load B for layer 0: 128 rows x 16 slots
    {
        const f16* src = Wt + ((size_t)0 * T + t) * 128 * 128;
#pragma unroll
        for (int k = 0; k < 8; ++k) {
            int c = tid + k * 256;          // 0..2047
            int r = c >> 4, sl = c & 15;
            uint4 v = *(const uint4*)(src + (size_t)r * 128 + sl * 8);
            *(uint4*)(&B[r][(sl ^ (r & 7)) * 8]) = v;
        }
    }
    __syncthreads();

    int wid = tid >> 6, lane = tid & 63;
    int lg = lane >> 4, lr = lane & 15;
    int m0 = wid * 16;
    int arow = m0 + lr;
    float pred[4] = {0.f, 0.f, 0.f, 0.f};
    int cur = 0;

    for (int l = 0; l < 4; ++l) {
        f16x8 afr[4];
#pragma unroll
        for (int ks = 0; ks < 4; ++ks) {
            int sl = (4 * ks + lg) ^ (arow & 7);
            afr[ks] = *(const f16x8*)(&A[cur][arow][sl * 8]);
        }
        const float* bias = bp + ((size_t)l * T + t) * 128;
#pragma unroll
        for (int nf = 0; nf < 8; ++nf) {
            int n = nf * 16 + lr;
            f32x4 acc = {0.f, 0.f, 0.f, 0.f};
#pragma unroll
            for (int ks = 0; ks < 4; ++ks) {
                int sl = (4 * ks + lg) ^ (n & 7);
                f16x8 bfr = *(const f16x8*)(&B[n][sl * 8]);
                acc = __builtin_amdgcn_mfma_f32_16x16x32_f16(afr[ks], bfr, acc, 0, 0, 0);
            }
            float bv = bias[n];
            if (l < 3) {
#pragma unroll
                for (int j = 0; j < 4; ++j) {
                    float y = acc[j] + bv;
                    y = y > 0.f ? y : 0.f;
                    int rr = m0 + 4 * lg + j;
                    A[cur ^ 1][rr][(((n >> 3) ^ (rr & 7)) << 3) + (n & 7)] = (f16)y;
                }
            } else {
                float w2 = oW2[t * 128 + n];
#pragma unroll
                for (int j = 0; j < 4; ++j) {
                    float z = acc[j] + bv;
                    z = z > 0.f ? z : 0.f;
                    pred[j] += z * w2;
                }
            }
        }
        __syncthreads();
        if (l < 3) {
            const f16* src = Wt + ((size_t)(l + 1) * T + t) * 128 * 128;
#pragma unroll
            for (int k = 0; k < 8; ++k) {
                int c = tid + k * 256;
                int r = c >> 4, sl = c & 15;
                uint4 v = *(const uint4*)(src + (size_t)r * 128 + sl * 8);
                *(uint4*)(&B[r][(sl ^ (r & 7)) * 8]) = v;
            }
            __syncthreads();
            cur ^= 1;
        }
    }

#pragma unroll
    for (int m = 1; m < 16; m <<= 1) {
#pragma unroll
        for (int j = 0; j < 4; ++j) pred[j] += __shfl_xor(pred[j], m, 64);
    }
    if (lr == 0) {
        float ob = ob2[t];
#pragma unroll
        for (int j = 0; j < 4; ++j) {
            int gg = g0 + m0 + 4 * lg + j;
            if (gg < G) out[(size_t)gg * T + t] = pred[j] + ob;
        }
    }
}

extern "C" void kernel_launch(void* const* d_in, const int* in_sizes, int n_in,
                              void* d_out, int out_size, void* d_ws, size_t ws_size,
                              hipStream_t stream) {
    const float* node_feats = (const float*)d_in[0];
    const int*   seg        = (const int*)d_in[1];
    const float* atom_w     = (const float*)d_in[3];
    const float* atom_b     = (const float*)d_in[4];
    const float* W1  = (const float*)d_in[5];
    const float* b1  = (const float*)d_in[6];
    const float* g1  = (const float*)d_in[7];
    const float* be1 = (const float*)d_in[8];
    const float* rm1 = (const float*)d_in[9];
    const float* rv1 = (const float*)d_in[10];
    const float* W2  = (const float*)d_in[11];
    const float* b2  = (const float*)d_in[12];
    const float* g2  = (const float*)d_in[13];
    const float* be2 = (const float*)d_in[14];
    const float* rm2 = (const float*)d_in[15];
    const float* rv2 = (const float*)d_in[16];
    const float* W3  = (const float*)d_in[17];
    const float* b3  = (const float*)d_in[18];
    const float* g3  = (const float*)d_in[19];
    const float* be3 = (const float*)d_in[20];
    const float* rm3 = (const float*)d_in[21];
    const float* rv3 = (const float*)d_in[22];
    const float* oW1 = (const float*)d_in[23];
    const float* ob1 = (const float*)d_in[24];
    const float* oW2 = (const float*)d_in[25];
    const float* ob2 = (const float*)d_in[26];

    int T = in_sizes[4];          // 12
    int F = in_sizes[3] / T;      // 128
    int N = in_sizes[0] / F;      // 1,000,000
    int G = out_size / T;         // 50,000

    char* ws = (char*)d_ws;
    size_t off = 0;
    int* start = (int*)ws;
    off += (((size_t)(G + 1) * 4) + 255) & ~(size_t)255;
    f16* Wt = (f16*)(ws + off);
    off += (((size_t)4 * T * 128 * 128 * 2) + 255) & ~(size_t)255;
    float* bp = (float*)(ws + off);
    off += (((size_t)4 * T * 128 * 4) + 255) & ~(size_t)255;
    f16* mol = (f16*)(ws + off);

    seg_starts_k<<<(N + 255) / 256, 256, 0, stream>>>(seg, N, G, start);
    prep_k<<<dim3(T, 4), 128, 0, stream>>>(W1, b1, W2, b2, W3, b3, oW1, ob1,
                                           g1, be1, rm1, rv1,
                                           g2, be2, rm2, rv2,
                                           g3, be3, rm3, rv3, Wt, bp);
    pool_k<<<(G + 3) / 4, 256, 0, stream>>>(node_feats, atom_w, atom_b, start, mol, G);
    fc_k<<<dim3((G + 63) / 64, T), 256, 0, stream>>>(mol, Wt, bp, oW2, ob2,
                                                     (float*)d_out, G, T);
}